// Round 2
// baseline (12596.983 us; speedup 1.0000x reference)
//
#include <hip/hip_runtime.h>
#include <math.h>

// N=50000 nodes, E=800000 edges, C=64, R=8, H=64, S=10
// Output row layout (512 floats/node): [mi0:64 | mi1:192 | res0:64 | res1:192]
// h0/h1 (linear_up) live temporarily in cols 256:512 of d_out; edge kernel
// accumulates T0/T1 into cols 0:256 via dst-sorted atomics; finalize reads
// both regions then overwrites 256:512 with res.
//
// d_ws layout: cnt/offs[int, N] | eids[int, E]   (~3.4 MB)

__device__ __forceinline__ float silu(float x) {
    return x / (1.0f + __expf(-x));
}

// ---------------- linear_up: h0 = nf0@Wup0, h1[n,o,i] = sum_c nf1[n,c,i]*Wup1[c,o]
__global__ __launch_bounds__(256) void up_kernel(
    const float* __restrict__ nf0, const float* __restrict__ nf1,
    const float* __restrict__ Wup0, const float* __restrict__ Wup1,
    float* __restrict__ out, int Nn) {
    __shared__ float sW0[4096];
    __shared__ float sW1u[4096];
    __shared__ float s0[4 * 64];
    __shared__ float s1[4 * 192];
    int t = threadIdx.x;
    for (int i = t; i < 4096; i += 256) { sW0[i] = Wup0[i]; sW1u[i] = Wup1[i]; }
    int n0 = blockIdx.x * 4;
    {
        int n = n0 + (t >> 6);
        s0[t] = (n < Nn) ? nf0[(size_t)n * 64 + (t & 63)] : 0.f;
    }
    for (int i = t; i < 768; i += 256) {
        int n = n0 + i / 192;
        s1[i] = (n < Nn) ? nf1[(size_t)n * 192 + (i % 192)] : 0.f;
    }
    __syncthreads();
    int w = t >> 6, o = t & 63;
    int n = n0 + w;
    if (n >= Nn) return;
    float a0 = 0.f, ax = 0.f, ay = 0.f, az = 0.f;
#pragma unroll 8
    for (int c = 0; c < 64; c++) {
        float w0 = sW0[c * 64 + o];
        float w1 = sW1u[c * 64 + o];
        float f0 = s0[w * 64 + c];
        a0 += f0 * w0;
        ax += s1[w * 192 + c * 3 + 0] * w1;
        ay += s1[w * 192 + c * 3 + 1] * w1;
        az += s1[w * 192 + c * 3 + 2] * w1;
    }
    float* row = out + (size_t)n * 512;
    row[256 + o] = a0;
    row[320 + o * 3 + 0] = ax;
    row[320 + o * 3 + 1] = ay;
    row[320 + o * 3 + 2] = az;
}

// ---------------- CSR build: count / scan / scatter
__global__ __launch_bounds__(256) void count_kernel(
    const int* __restrict__ ei, int* __restrict__ cnt, int E) {
    int e = blockIdx.x * 256 + threadIdx.x;
    if (e < E) atomicAdd(&cnt[ei[(size_t)E + e]], 1);
}

__global__ __launch_bounds__(1024) void scan_kernel(int* __restrict__ data, int n) {
    __shared__ int part[1024];
    int t = threadIdx.x;
    const int chunk = (n + 1023) / 1024;   // 49 for n=50000
    int lo = t * chunk;
    int hi = lo + chunk; if (hi > n) hi = n;
    int vals[64];
    int sum = 0;
    for (int i = lo; i < hi; i++) { int v = data[i]; vals[i - lo] = v; sum += v; }
    part[t] = sum;
    __syncthreads();
    for (int off = 1; off < 1024; off <<= 1) {
        int v = (t >= off) ? part[t - off] : 0;
        __syncthreads();
        part[t] += v;
        __syncthreads();
    }
    int base = (t == 0) ? 0 : part[t - 1];
    for (int i = lo; i < hi; i++) { data[i] = base; base += vals[i - lo]; }
}

__global__ __launch_bounds__(256) void scatter_kernel(
    const int* __restrict__ ei, int* __restrict__ offs,
    int* __restrict__ eids, int E) {
    int e = blockIdx.x * 256 + threadIdx.x;
    if (e < E) {
        int pos = atomicAdd(&offs[ei[(size_t)E + e]], 1);
        eids[pos] = e;
    }
}

// ---------------- fused radial-MLP + tensor-product + sorted atomic scatter
// 2 consecutive (dst-sorted) edges per thread. W1/W2 read via wave-uniform
// indices from global -> compiler scalarizes to s_load (SMEM pipe, no LDS).
__global__ __launch_bounds__(256, 2) void edge_kernel(
    const float* __restrict__ edge_feats, const float* __restrict__ edge_attrs1,
    const float* __restrict__ cutoff, const int* __restrict__ edge_index,
    const float* __restrict__ W1g, const float* __restrict__ W2g,
    const int* __restrict__ eids, float* __restrict__ out, int E) {
    int gid = blockIdx.x * 256 + threadIdx.x;
    int s0 = gid * 2;
    if (s0 >= E) return;
    int s1 = s0 + 1;
    bool have1 = (s1 < E);
    int e0, e1;
    if (eids) {
        e0 = eids[s0];
        e1 = have1 ? eids[s1] : e0;
    } else {
        e0 = s0;
        e1 = have1 ? s1 : e0;
    }

    // ---- radial hidden for both edges: hid = silu(ef @ W1)
    float ef0[8], ef1[8];
    {
        const float4* p0 = reinterpret_cast<const float4*>(edge_feats + (size_t)e0 * 8);
        const float4* p1 = reinterpret_cast<const float4*>(edge_feats + (size_t)e1 * 8);
        float4 a = p0[0], b = p0[1], c = p1[0], d = p1[1];
        ef0[0] = a.x; ef0[1] = a.y; ef0[2] = a.z; ef0[3] = a.w;
        ef0[4] = b.x; ef0[5] = b.y; ef0[6] = b.z; ef0[7] = b.w;
        ef1[0] = c.x; ef1[1] = c.y; ef1[2] = c.z; ef1[3] = c.w;
        ef1[4] = d.x; ef1[5] = d.y; ef1[6] = d.z; ef1[7] = d.w;
    }
    float hid0[64], hid1[64];
    const float4* w1v = reinterpret_cast<const float4*>(W1g);
#pragma unroll
    for (int hg = 0; hg < 16; hg++) {
        float a0 = 0.f, a1 = 0.f, a2 = 0.f, a3 = 0.f;
        float b0 = 0.f, b1 = 0.f, b2 = 0.f, b3 = 0.f;
#pragma unroll
        for (int r = 0; r < 8; r++) {
            float4 wv = w1v[r * 16 + hg];      // wave-uniform -> s_load
            a0 += ef0[r] * wv.x; a1 += ef0[r] * wv.y;
            a2 += ef0[r] * wv.z; a3 += ef0[r] * wv.w;
            b0 += ef1[r] * wv.x; b1 += ef1[r] * wv.y;
            b2 += ef1[r] * wv.z; b3 += ef1[r] * wv.w;
        }
        hid0[hg * 4 + 0] = silu(a0); hid0[hg * 4 + 1] = silu(a1);
        hid0[hg * 4 + 2] = silu(a2); hid0[hg * 4 + 3] = silu(a3);
        hid1[hg * 4 + 0] = silu(b0); hid1[hg * 4 + 1] = silu(b1);
        hid1[hg * 4 + 2] = silu(b2); hid1[hg * 4 + 3] = silu(b3);
    }

    int src0 = edge_index[e0], dst0 = edge_index[(size_t)E + e0];
    int src1 = edge_index[e1], dst1 = edge_index[(size_t)E + e1];
    float cut0 = cutoff[e0], cut1 = cutoff[e1];
    float u0 = edge_attrs1[(size_t)e0 * 3 + 0];
    float u1 = edge_attrs1[(size_t)e0 * 3 + 1];
    float u2 = edge_attrs1[(size_t)e0 * 3 + 2];
    float v0 = edge_attrs1[(size_t)e1 * 3 + 0];
    float v1 = edge_attrs1[(size_t)e1 * 3 + 1];
    float v2 = edge_attrs1[(size_t)e1 * 3 + 2];
    if (!have1) { cut1 = 0.f; }  // duplicate edge contributes nothing
    const float* h0r0 = out + (size_t)src0 * 512 + 256;
    const float* h1r0 = out + (size_t)src0 * 512 + 320;
    const float* h0r1 = out + (size_t)src1 * 512 + 256;
    const float* h1r1 = out + (size_t)src1 * 512 + 320;
    float* outr0 = out + (size_t)dst0 * 512;
    float* outr1 = out + (size_t)dst1 * 512;
    const float4* w2v = reinterpret_cast<const float4*>(W2g);

#pragma unroll 1
    for (int cg = 0; cg < 16; cg++) {
        float p00[4] = {0,0,0,0}, p11[4] = {0,0,0,0}, p01[4] = {0,0,0,0}, p10[4] = {0,0,0,0};
        float q00[4] = {0,0,0,0}, q11[4] = {0,0,0,0}, q01[4] = {0,0,0,0}, q10[4] = {0,0,0,0};
#pragma unroll
        for (int l = 0; l < 64; l++) {
            float4 wa = w2v[l * 64 + cg];            // wave-uniform -> s_load
            float4 wb = w2v[l * 64 + 16 + cg];
            float4 wc = w2v[l * 64 + 32 + cg];
            float4 wd = w2v[l * 64 + 48 + cg];
            float h0l = hid0[l], h1l = hid1[l];
            p00[0] += h0l * wa.x; p00[1] += h0l * wa.y; p00[2] += h0l * wa.z; p00[3] += h0l * wa.w;
            p11[0] += h0l * wb.x; p11[1] += h0l * wb.y; p11[2] += h0l * wb.z; p11[3] += h0l * wb.w;
            p01[0] += h0l * wc.x; p01[1] += h0l * wc.y; p01[2] += h0l * wc.z; p01[3] += h0l * wc.w;
            p10[0] += h0l * wd.x; p10[1] += h0l * wd.y; p10[2] += h0l * wd.z; p10[3] += h0l * wd.w;
            q00[0] += h1l * wa.x; q00[1] += h1l * wa.y; q00[2] += h1l * wa.z; q00[3] += h1l * wa.w;
            q11[0] += h1l * wb.x; q11[1] += h1l * wb.y; q11[2] += h1l * wb.z; q11[3] += h1l * wb.w;
            q01[0] += h1l * wc.x; q01[1] += h1l * wc.y; q01[2] += h1l * wc.z; q01[3] += h1l * wc.w;
            q10[0] += h1l * wd.x; q10[1] += h1l * wd.y; q10[2] += h1l * wd.z; q10[3] += h1l * wd.w;
        }
        int c0 = cg * 4;
        float4 h0a = *reinterpret_cast<const float4*>(h0r0 + c0);
        float4 r0 = *reinterpret_cast<const float4*>(h1r0 + c0 * 3);
        float4 r1 = *reinterpret_cast<const float4*>(h1r0 + c0 * 3 + 4);
        float4 r2 = *reinterpret_cast<const float4*>(h1r0 + c0 * 3 + 8);
        float4 h0b = *reinterpret_cast<const float4*>(h0r1 + c0);
        float4 t0 = *reinterpret_cast<const float4*>(h1r1 + c0 * 3);
        float4 t1 = *reinterpret_cast<const float4*>(h1r1 + c0 * 3 + 4);
        float4 t2 = *reinterpret_cast<const float4*>(h1r1 + c0 * 3 + 8);
        float h0e0[4] = {h0a.x, h0a.y, h0a.z, h0a.w};
        float h1e0[12] = {r0.x, r0.y, r0.z, r0.w, r1.x, r1.y, r1.z, r1.w, r2.x, r2.y, r2.z, r2.w};
        float h0e1[4] = {h0b.x, h0b.y, h0b.z, h0b.w};
        float h1e1[12] = {t0.x, t0.y, t0.z, t0.w, t1.x, t1.y, t1.z, t1.w, t2.x, t2.y, t2.z, t2.w};
#pragma unroll
        for (int k = 0; k < 4; k++) {
            int c = c0 + k;
            {   // edge 0
                float he0 = h0e0[k];
                float x0 = h1e0[k * 3 + 0], x1 = h1e0[k * 3 + 1], x2 = h1e0[k * 3 + 2];
                float d = x0 * u0 + x1 * u1 + x2 * u2;
                float m0 = (p00[k] * he0 + p11[k] * d) * cut0;
                float wa2 = p01[k] * he0 * cut0;
                float wb2 = p10[k] * cut0;
                atomicAdd(outr0 + c, m0);
                atomicAdd(outr0 + 64 + c * 3 + 0, wa2 * u0 + wb2 * x0);
                atomicAdd(outr0 + 64 + c * 3 + 1, wa2 * u1 + wb2 * x1);
                atomicAdd(outr0 + 64 + c * 3 + 2, wa2 * u2 + wb2 * x2);
            }
            {   // edge 1
                float he0 = h0e1[k];
                float x0 = h1e1[k * 3 + 0], x1 = h1e1[k * 3 + 1], x2 = h1e1[k * 3 + 2];
                float d = x0 * v0 + x1 * v1 + x2 * v2;
                float m0 = (q00[k] * he0 + q11[k] * d) * cut1;
                float wa2 = q01[k] * he0 * cut1;
                float wb2 = q10[k] * cut1;
                atomicAdd(outr1 + c, m0);
                atomicAdd(outr1 + 64 + c * 3 + 0, wa2 * v0 + wb2 * x0);
                atomicAdd(outr1 + 64 + c * 3 + 1, wa2 * v1 + wb2 * x1);
                atomicAdd(outr1 + 64 + c * 3 + 2, wa2 * v2 + wb2 * x2);
            }
        }
    }
}

// ---------------- finalize: scale by 1/16, apply Q0/Q1, species residual
__global__ __launch_bounds__(256) void finalize_kernel(
    const float* __restrict__ node_attrs, const float* __restrict__ Wsc0,
    const float* __restrict__ Wsc1, const float* __restrict__ Q0,
    const float* __restrict__ Q1, float* __restrict__ out, int Nn) {
    __shared__ float smi0[4][64];
    __shared__ float smi1[4][192];
    int t = threadIdx.x;
    int w = t >> 6, o = t & 63;
    int n = blockIdx.x * 4 + w;
    const float inv = 1.0f / 16.0f;  // AVG_NUM_NEIGHBORS
    float q00 = Q0[0];
    float Q[9];
#pragma unroll
    for (int i = 0; i < 9; i++) Q[i] = Q1[i];
    if (n < Nn) {
        float* row = out + (size_t)n * 512;
        float t0 = row[o];
        float ta = row[64 + o * 3 + 0];
        float tb = row[64 + o * 3 + 1];
        float tc = row[64 + o * 3 + 2];
        float mi0 = t0 * inv * q00;
        float m0i = inv * (ta * Q[0] + tb * Q[3] + tc * Q[6]);
        float m1i = inv * (ta * Q[1] + tb * Q[4] + tc * Q[7]);
        float m2i = inv * (ta * Q[2] + tb * Q[5] + tc * Q[8]);
        row[o] = mi0;
        row[64 + o * 3 + 0] = m0i;
        row[64 + o * 3 + 1] = m1i;
        row[64 + o * 3 + 2] = m2i;
        smi0[w][o] = mi0;
        smi1[w][o * 3 + 0] = m0i;
        smi1[w][o * 3 + 1] = m1i;
        smi1[w][o * 3 + 2] = m2i;
    }
    __syncthreads();
    if (n >= Nn) return;
    float acc0 = 0.f, acc1x = 0.f, acc1y = 0.f, acc1z = 0.f;
    for (int s = 0; s < 10; s++) {
        float a = node_attrs[(size_t)n * 10 + s];
        if (a != 0.f) {
            const float* w0 = Wsc0 + s * 4096;
            const float* w1 = Wsc1 + s * 4096;
            float p0 = 0.f, px = 0.f, py = 0.f, pz = 0.f;
#pragma unroll 8
            for (int c = 0; c < 64; c++) {
                float vv0 = w0[c * 64 + o];
                float vv1 = w1[c * 64 + o];
                p0 += smi0[w][c] * vv0;
                px += smi1[w][c * 3 + 0] * vv1;
                py += smi1[w][c * 3 + 1] * vv1;
                pz += smi1[w][c * 3 + 2] * vv1;
            }
            acc0 += a * p0; acc1x += a * px; acc1y += a * py; acc1z += a * pz;
        }
    }
    float* row = out + (size_t)n * 512;
    row[256 + o] = acc0;
    row[320 + o * 3 + 0] = acc1x;
    row[320 + o * 3 + 1] = acc1y;
    row[320 + o * 3 + 2] = acc1z;
}

extern "C" void kernel_launch(void* const* d_in, const int* in_sizes, int n_in,
                              void* d_out, int out_size, void* d_ws, size_t ws_size,
                              hipStream_t stream) {
    const float* nf0   = (const float*)d_in[0];
    const float* nf1   = (const float*)d_in[1];
    const float* attrs = (const float*)d_in[2];
    const float* ef    = (const float*)d_in[3];
    const float* ea1   = (const float*)d_in[4];
    const float* cut   = (const float*)d_in[5];
    const float* Wup0  = (const float*)d_in[6];
    const float* Wup1  = (const float*)d_in[7];
    const float* W1    = (const float*)d_in[8];
    const float* W2    = (const float*)d_in[9];
    const float* Wsc0  = (const float*)d_in[10];
    const float* Wsc1  = (const float*)d_in[11];
    const float* Q0    = (const float*)d_in[12];
    const float* Q1    = (const float*)d_in[13];
    const int*   ei    = (const int*)d_in[14];
    int Nn = in_sizes[0] / 64;      // 50000
    int E  = in_sizes[14] / 2;      // 800000
    float* out = (float*)d_out;

    size_t need = ((size_t)Nn + (size_t)E) * sizeof(int);
    bool useSort = (ws_size >= need);
    int* cnt  = (int*)d_ws;          // [Nn]
    int* eids = cnt + Nn;            // [E]

    hipMemsetAsync(out, 0, (size_t)out_size * sizeof(float), stream);
    up_kernel<<<(Nn + 3) / 4, 256, 0, stream>>>(nf0, nf1, Wup0, Wup1, out, Nn);
    if (useSort) {
        hipMemsetAsync(cnt, 0, (size_t)Nn * sizeof(int), stream);
        count_kernel<<<(E + 255) / 256, 256, 0, stream>>>(ei, cnt, E);
        scan_kernel<<<1, 1024, 0, stream>>>(cnt, Nn);
        scatter_kernel<<<(E + 255) / 256, 256, 0, stream>>>(ei, cnt, eids, E);
    }
    int nthreads = (E + 1) / 2;
    edge_kernel<<<(nthreads + 255) / 256, 256, 0, stream>>>(
        ef, ea1, cut, ei, W1, W2, useSort ? eids : nullptr, out, E);
    finalize_kernel<<<(Nn + 3) / 4, 256, 0, stream>>>(attrs, Wsc0, Wsc1, Q0, Q1, out, Nn);
}

// Round 3
// 10858.872 us; speedup vs baseline: 1.1601x; 1.1601x over previous
//
#include <hip/hip_runtime.h>
#include <math.h>

// N=50000 nodes, E=800000 edges, C=64, R=8, H=64, S=10
// Output row layout (512 floats/node): [mi0:64 | mi1:192 | res0:64 | res1:192]
// h0/h1 (linear_up) live temporarily in cols 256:512 of d_out.
//
// Fast path (needs ~823 MB ws):
//   d_ws: cnt[int Nn] | eids[int E] | (256B align) | msg[float E*256]
//   count/scan/scatter -> dst-sorted eids + end-offsets in cnt
//   msg_kernel: per sorted edge, compute 256-float message, coalesced store
//   gather_kernel: per node, sum its contiguous message rows -> out[0:256]
//   finalize: 1/16, Q projection, species residual -> out[256:512]
// Fallback (small ws): atomic scatter (slow but correct).

__device__ __forceinline__ float silu(float x) {
    return x / (1.0f + __expf(-x));
}

// ---------------- linear_up: h0 = nf0@Wup0, h1[n,o,i] = sum_c nf1[n,c,i]*Wup1[c,o]
__global__ __launch_bounds__(256) void up_kernel(
    const float* __restrict__ nf0, const float* __restrict__ nf1,
    const float* __restrict__ Wup0, const float* __restrict__ Wup1,
    float* __restrict__ out, int Nn) {
    __shared__ float sW0[4096];
    __shared__ float sW1u[4096];
    __shared__ float s0[4 * 64];
    __shared__ float s1[4 * 192];
    int t = threadIdx.x;
    for (int i = t; i < 4096; i += 256) { sW0[i] = Wup0[i]; sW1u[i] = Wup1[i]; }
    int n0 = blockIdx.x * 4;
    {
        int n = n0 + (t >> 6);
        s0[t] = (n < Nn) ? nf0[(size_t)n * 64 + (t & 63)] : 0.f;
    }
    for (int i = t; i < 768; i += 256) {
        int n = n0 + i / 192;
        s1[i] = (n < Nn) ? nf1[(size_t)n * 192 + (i % 192)] : 0.f;
    }
    __syncthreads();
    int w = t >> 6, o = t & 63;
    int n = n0 + w;
    if (n >= Nn) return;
    float a0 = 0.f, ax = 0.f, ay = 0.f, az = 0.f;
#pragma unroll 8
    for (int c = 0; c < 64; c++) {
        float w0 = sW0[c * 64 + o];
        float w1 = sW1u[c * 64 + o];
        float f0 = s0[w * 64 + c];
        a0 += f0 * w0;
        ax += s1[w * 192 + c * 3 + 0] * w1;
        ay += s1[w * 192 + c * 3 + 1] * w1;
        az += s1[w * 192 + c * 3 + 2] * w1;
    }
    float* row = out + (size_t)n * 512;
    row[256 + o] = a0;
    row[320 + o * 3 + 0] = ax;
    row[320 + o * 3 + 1] = ay;
    row[320 + o * 3 + 2] = az;
}

// ---------------- CSR build: count / scan / scatter (verified in round 2)
__global__ __launch_bounds__(256) void count_kernel(
    const int* __restrict__ ei, int* __restrict__ cnt, int E) {
    int e = blockIdx.x * 256 + threadIdx.x;
    if (e < E) atomicAdd(&cnt[ei[(size_t)E + e]], 1);
}

__global__ __launch_bounds__(1024) void scan_kernel(int* __restrict__ data, int n) {
    __shared__ int part[1024];
    int t = threadIdx.x;
    const int chunk = (n + 1023) / 1024;   // 49 for n=50000
    int lo = t * chunk;
    int hi = lo + chunk; if (hi > n) hi = n;
    int vals[64];
    int sum = 0;
    for (int i = lo; i < hi; i++) { int v = data[i]; vals[i - lo] = v; sum += v; }
    part[t] = sum;
    __syncthreads();
    for (int off = 1; off < 1024; off <<= 1) {
        int v = (t >= off) ? part[t - off] : 0;
        __syncthreads();
        part[t] += v;
        __syncthreads();
    }
    int base = (t == 0) ? 0 : part[t - 1];
    for (int i = lo; i < hi; i++) { data[i] = base; base += vals[i - lo]; }
}

__global__ __launch_bounds__(256) void scatter_kernel(
    const int* __restrict__ ei, int* __restrict__ offs,
    int* __restrict__ eids, int E) {
    int e = blockIdx.x * 256 + threadIdx.x;
    if (e < E) {
        int pos = atomicAdd(&offs[ei[(size_t)E + e]], 1);
        eids[pos] = e;
    }
    // after this kernel offs[n] holds the END offset of node n's segment
}

// ---------------- Phase 1: per-edge message -> coalesced rows in sorted order
__global__ __launch_bounds__(256) void msg_kernel(
    const float* __restrict__ edge_feats, const float* __restrict__ edge_attrs1,
    const float* __restrict__ cutoff, const int* __restrict__ edge_index,
    const float* __restrict__ W1g, const float* __restrict__ W2g,
    const int* __restrict__ eids, const float* __restrict__ out,
    float* __restrict__ msg, int E) {
    int gid = blockIdx.x * 256 + threadIdx.x;
    if (gid >= E) return;
    int e = eids[gid];

    float ef[8];
    {
        const float4* p = reinterpret_cast<const float4*>(edge_feats + (size_t)e * 8);
        float4 a = p[0], b = p[1];
        ef[0] = a.x; ef[1] = a.y; ef[2] = a.z; ef[3] = a.w;
        ef[4] = b.x; ef[5] = b.y; ef[6] = b.z; ef[7] = b.w;
    }
    float hid[64];
    const float4* w1v = reinterpret_cast<const float4*>(W1g);
#pragma unroll
    for (int hg = 0; hg < 16; hg++) {
        float a0 = 0.f, a1 = 0.f, a2 = 0.f, a3 = 0.f;
#pragma unroll
        for (int r = 0; r < 8; r++) {
            float4 wv = w1v[r * 16 + hg];      // wave-uniform
            a0 += ef[r] * wv.x; a1 += ef[r] * wv.y;
            a2 += ef[r] * wv.z; a3 += ef[r] * wv.w;
        }
        hid[hg * 4 + 0] = silu(a0); hid[hg * 4 + 1] = silu(a1);
        hid[hg * 4 + 2] = silu(a2); hid[hg * 4 + 3] = silu(a3);
    }

    int src = edge_index[e];
    float cut = cutoff[e];
    float u0 = edge_attrs1[(size_t)e * 3 + 0];
    float u1 = edge_attrs1[(size_t)e * 3 + 1];
    float u2 = edge_attrs1[(size_t)e * 3 + 2];
    const float* h0r = out + (size_t)src * 512 + 256;
    const float* h1r = out + (size_t)src * 512 + 320;
    float* mrow = msg + (size_t)gid * 256;
    const float4* w2v = reinterpret_cast<const float4*>(W2g);

#pragma unroll 1
    for (int cg = 0; cg < 16; cg++) {
        float p00[4] = {0,0,0,0}, p11[4] = {0,0,0,0}, p01[4] = {0,0,0,0}, p10[4] = {0,0,0,0};
#pragma unroll
        for (int l = 0; l < 64; l++) {
            float4 wa = w2v[l * 64 + cg];            // wave-uniform
            float4 wb = w2v[l * 64 + 16 + cg];
            float4 wc = w2v[l * 64 + 32 + cg];
            float4 wd = w2v[l * 64 + 48 + cg];
            float hl = hid[l];
            p00[0] += hl * wa.x; p00[1] += hl * wa.y; p00[2] += hl * wa.z; p00[3] += hl * wa.w;
            p11[0] += hl * wb.x; p11[1] += hl * wb.y; p11[2] += hl * wb.z; p11[3] += hl * wb.w;
            p01[0] += hl * wc.x; p01[1] += hl * wc.y; p01[2] += hl * wc.z; p01[3] += hl * wc.w;
            p10[0] += hl * wd.x; p10[1] += hl * wd.y; p10[2] += hl * wd.z; p10[3] += hl * wd.w;
        }
        int c0 = cg * 4;
        float4 h0v = *reinterpret_cast<const float4*>(h0r + c0);
        float4 r0 = *reinterpret_cast<const float4*>(h1r + c0 * 3);
        float4 r1 = *reinterpret_cast<const float4*>(h1r + c0 * 3 + 4);
        float4 r2 = *reinterpret_cast<const float4*>(h1r + c0 * 3 + 8);
        float h0a[4] = {h0v.x, h0v.y, h0v.z, h0v.w};
        float h1a[12] = {r0.x, r0.y, r0.z, r0.w, r1.x, r1.y, r1.z, r1.w, r2.x, r2.y, r2.z, r2.w};
        float m0v[4];
        float m1v[12];
#pragma unroll
        for (int k = 0; k < 4; k++) {
            float he0 = h0a[k];
            float x0 = h1a[k * 3 + 0], x1 = h1a[k * 3 + 1], x2 = h1a[k * 3 + 2];
            float d = x0 * u0 + x1 * u1 + x2 * u2;
            m0v[k] = (p00[k] * he0 + p11[k] * d) * cut;
            float wa2 = p01[k] * he0 * cut;
            float wb2 = p10[k] * cut;
            m1v[k * 3 + 0] = wa2 * u0 + wb2 * x0;
            m1v[k * 3 + 1] = wa2 * u1 + wb2 * x1;
            m1v[k * 3 + 2] = wa2 * u2 + wb2 * x2;
        }
        // store: m0 at [c0..c0+3], m1 at [64 + c0*3 .. +12)  (both 16B aligned)
        *reinterpret_cast<float4*>(mrow + c0) = make_float4(m0v[0], m0v[1], m0v[2], m0v[3]);
        float4* m1p = reinterpret_cast<float4*>(mrow + 64 + c0 * 3);
        m1p[0] = make_float4(m1v[0], m1v[1], m1v[2], m1v[3]);
        m1p[1] = make_float4(m1v[4], m1v[5], m1v[6], m1v[7]);
        m1p[2] = make_float4(m1v[8], m1v[9], m1v[10], m1v[11]);
    }
}

// ---------------- Phase 2: per-node sum of contiguous message rows
__global__ __launch_bounds__(256) void gather_kernel(
    const int* __restrict__ cntEnd, const float* __restrict__ msg,
    float* __restrict__ out, int Nn) {
    int t = threadIdx.x;
    int w = t >> 6, lane = t & 63;
    int n = blockIdx.x * 4 + w;
    if (n >= Nn) return;
    int beg = (n == 0) ? 0 : cntEnd[n - 1];
    int end = cntEnd[n];
    float4 acc = make_float4(0.f, 0.f, 0.f, 0.f);
    float4 acc2 = make_float4(0.f, 0.f, 0.f, 0.f);
    const float* base = msg + (size_t)beg * 256 + lane * 4;
    int cnt = end - beg;
    int i = 0;
    for (; i + 1 < cnt; i += 2) {
        float4 v0 = *reinterpret_cast<const float4*>(base);
        float4 v1 = *reinterpret_cast<const float4*>(base + 256);
        base += 512;
        acc.x += v0.x; acc.y += v0.y; acc.z += v0.z; acc.w += v0.w;
        acc2.x += v1.x; acc2.y += v1.y; acc2.z += v1.z; acc2.w += v1.w;
    }
    if (i < cnt) {
        float4 v0 = *reinterpret_cast<const float4*>(base);
        acc.x += v0.x; acc.y += v0.y; acc.z += v0.z; acc.w += v0.w;
    }
    acc.x += acc2.x; acc.y += acc2.y; acc.z += acc2.z; acc.w += acc2.w;
    // raw T (finalize applies 1/16 and Q)
    *reinterpret_cast<float4*>(out + (size_t)n * 512 + lane * 4) = acc;
}

// ---------------- fallback: unsorted atomic scatter (only if ws too small)
__global__ __launch_bounds__(256) void atomic_edge_kernel(
    const float* __restrict__ edge_feats, const float* __restrict__ edge_attrs1,
    const float* __restrict__ cutoff, const int* __restrict__ edge_index,
    const float* __restrict__ W1g, const float* __restrict__ W2g,
    float* __restrict__ out, int E) {
    int e = blockIdx.x * 256 + threadIdx.x;
    if (e >= E) return;
    float ef[8];
    {
        const float4* p = reinterpret_cast<const float4*>(edge_feats + (size_t)e * 8);
        float4 a = p[0], b = p[1];
        ef[0] = a.x; ef[1] = a.y; ef[2] = a.z; ef[3] = a.w;
        ef[4] = b.x; ef[5] = b.y; ef[6] = b.z; ef[7] = b.w;
    }
    float hid[64];
    const float4* w1v = reinterpret_cast<const float4*>(W1g);
#pragma unroll
    for (int hg = 0; hg < 16; hg++) {
        float a0 = 0.f, a1 = 0.f, a2 = 0.f, a3 = 0.f;
#pragma unroll
        for (int r = 0; r < 8; r++) {
            float4 wv = w1v[r * 16 + hg];
            a0 += ef[r] * wv.x; a1 += ef[r] * wv.y;
            a2 += ef[r] * wv.z; a3 += ef[r] * wv.w;
        }
        hid[hg * 4 + 0] = silu(a0); hid[hg * 4 + 1] = silu(a1);
        hid[hg * 4 + 2] = silu(a2); hid[hg * 4 + 3] = silu(a3);
    }
    int src = edge_index[e], dst = edge_index[(size_t)E + e];
    float cut = cutoff[e];
    float u0 = edge_attrs1[(size_t)e * 3 + 0];
    float u1 = edge_attrs1[(size_t)e * 3 + 1];
    float u2 = edge_attrs1[(size_t)e * 3 + 2];
    const float* h0r = out + (size_t)src * 512 + 256;
    const float* h1r = out + (size_t)src * 512 + 320;
    float* outr = out + (size_t)dst * 512;
    const float4* w2v = reinterpret_cast<const float4*>(W2g);
#pragma unroll 1
    for (int cg = 0; cg < 16; cg++) {
        float p00[4] = {0,0,0,0}, p11[4] = {0,0,0,0}, p01[4] = {0,0,0,0}, p10[4] = {0,0,0,0};
#pragma unroll
        for (int l = 0; l < 64; l++) {
            float4 wa = w2v[l * 64 + cg];
            float4 wb = w2v[l * 64 + 16 + cg];
            float4 wc = w2v[l * 64 + 32 + cg];
            float4 wd = w2v[l * 64 + 48 + cg];
            float hl = hid[l];
            p00[0] += hl * wa.x; p00[1] += hl * wa.y; p00[2] += hl * wa.z; p00[3] += hl * wa.w;
            p11[0] += hl * wb.x; p11[1] += hl * wb.y; p11[2] += hl * wb.z; p11[3] += hl * wb.w;
            p01[0] += hl * wc.x; p01[1] += hl * wc.y; p01[2] += hl * wc.z; p01[3] += hl * wc.w;
            p10[0] += hl * wd.x; p10[1] += hl * wd.y; p10[2] += hl * wd.z; p10[3] += hl * wd.w;
        }
        int c0 = cg * 4;
        float4 h0v = *reinterpret_cast<const float4*>(h0r + c0);
        float4 r0 = *reinterpret_cast<const float4*>(h1r + c0 * 3);
        float4 r1 = *reinterpret_cast<const float4*>(h1r + c0 * 3 + 4);
        float4 r2 = *reinterpret_cast<const float4*>(h1r + c0 * 3 + 8);
        float h0a[4] = {h0v.x, h0v.y, h0v.z, h0v.w};
        float h1a[12] = {r0.x, r0.y, r0.z, r0.w, r1.x, r1.y, r1.z, r1.w, r2.x, r2.y, r2.z, r2.w};
#pragma unroll
        for (int k = 0; k < 4; k++) {
            int c = c0 + k;
            float he0 = h0a[k];
            float x0 = h1a[k * 3 + 0], x1 = h1a[k * 3 + 1], x2 = h1a[k * 3 + 2];
            float d = x0 * u0 + x1 * u1 + x2 * u2;
            float m0 = (p00[k] * he0 + p11[k] * d) * cut;
            float wa2 = p01[k] * he0 * cut;
            float wb2 = p10[k] * cut;
            atomicAdd(outr + c, m0);
            atomicAdd(outr + 64 + c * 3 + 0, wa2 * u0 + wb2 * x0);
            atomicAdd(outr + 64 + c * 3 + 1, wa2 * u1 + wb2 * x1);
            atomicAdd(outr + 64 + c * 3 + 2, wa2 * u2 + wb2 * x2);
        }
    }
}

// ---------------- finalize: scale by 1/16, apply Q0/Q1, species residual
__global__ __launch_bounds__(256) void finalize_kernel(
    const float* __restrict__ node_attrs, const float* __restrict__ Wsc0,
    const float* __restrict__ Wsc1, const float* __restrict__ Q0,
    const float* __restrict__ Q1, float* __restrict__ out, int Nn) {
    __shared__ float smi0[4][64];
    __shared__ float smi1[4][192];
    int t = threadIdx.x;
    int w = t >> 6, o = t & 63;
    int n = blockIdx.x * 4 + w;
    const float inv = 1.0f / 16.0f;  // AVG_NUM_NEIGHBORS
    float q00 = Q0[0];
    float Q[9];
#pragma unroll
    for (int i = 0; i < 9; i++) Q[i] = Q1[i];
    if (n < Nn) {
        float* row = out + (size_t)n * 512;
        float t0 = row[o];
        float ta = row[64 + o * 3 + 0];
        float tb = row[64 + o * 3 + 1];
        float tc = row[64 + o * 3 + 2];
        float mi0 = t0 * inv * q00;
        float m0i = inv * (ta * Q[0] + tb * Q[3] + tc * Q[6]);
        float m1i = inv * (ta * Q[1] + tb * Q[4] + tc * Q[7]);
        float m2i = inv * (ta * Q[2] + tb * Q[5] + tc * Q[8]);
        row[o] = mi0;
        row[64 + o * 3 + 0] = m0i;
        row[64 + o * 3 + 1] = m1i;
        row[64 + o * 3 + 2] = m2i;
        smi0[w][o] = mi0;
        smi1[w][o * 3 + 0] = m0i;
        smi1[w][o * 3 + 1] = m1i;
        smi1[w][o * 3 + 2] = m2i;
    }
    __syncthreads();
    if (n >= Nn) return;
    float acc0 = 0.f, acc1x = 0.f, acc1y = 0.f, acc1z = 0.f;
    for (int s = 0; s < 10; s++) {
        float a = node_attrs[(size_t)n * 10 + s];
        if (a != 0.f) {
            const float* w0 = Wsc0 + s * 4096;
            const float* w1 = Wsc1 + s * 4096;
            float p0 = 0.f, px = 0.f, py = 0.f, pz = 0.f;
#pragma unroll 8
            for (int c = 0; c < 64; c++) {
                float vv0 = w0[c * 64 + o];
                float vv1 = w1[c * 64 + o];
                p0 += smi0[w][c] * vv0;
                px += smi1[w][c * 3 + 0] * vv1;
                py += smi1[w][c * 3 + 1] * vv1;
                pz += smi1[w][c * 3 + 2] * vv1;
            }
            acc0 += a * p0; acc1x += a * px; acc1y += a * py; acc1z += a * pz;
        }
    }
    float* row = out + (size_t)n * 512;
    row[256 + o] = acc0;
    row[320 + o * 3 + 0] = acc1x;
    row[320 + o * 3 + 1] = acc1y;
    row[320 + o * 3 + 2] = acc1z;
}

extern "C" void kernel_launch(void* const* d_in, const int* in_sizes, int n_in,
                              void* d_out, int out_size, void* d_ws, size_t ws_size,
                              hipStream_t stream) {
    const float* nf0   = (const float*)d_in[0];
    const float* nf1   = (const float*)d_in[1];
    const float* attrs = (const float*)d_in[2];
    const float* ef    = (const float*)d_in[3];
    const float* ea1   = (const float*)d_in[4];
    const float* cut   = (const float*)d_in[5];
    const float* Wup0  = (const float*)d_in[6];
    const float* Wup1  = (const float*)d_in[7];
    const float* W1    = (const float*)d_in[8];
    const float* W2    = (const float*)d_in[9];
    const float* Wsc0  = (const float*)d_in[10];
    const float* Wsc1  = (const float*)d_in[11];
    const float* Q0    = (const float*)d_in[12];
    const float* Q1    = (const float*)d_in[13];
    const int*   ei    = (const int*)d_in[14];
    int Nn = in_sizes[0] / 64;      // 50000
    int E  = in_sizes[14] / 2;      // 800000
    float* out = (float*)d_out;

    size_t intBytes = ((size_t)Nn + (size_t)E) * sizeof(int);
    size_t msgOff = (intBytes + 255) & ~(size_t)255;
    size_t needFull = msgOff + (size_t)E * 256 * sizeof(float);

    up_kernel<<<(Nn + 3) / 4, 256, 0, stream>>>(nf0, nf1, Wup0, Wup1, out, Nn);

    if (ws_size >= needFull) {
        int* cnt  = (int*)d_ws;                               // [Nn] -> end offsets
        int* eids = cnt + Nn;                                 // [E] sorted edge ids
        float* msg = (float*)((char*)d_ws + msgOff);          // [E][256]
        hipMemsetAsync(cnt, 0, (size_t)Nn * sizeof(int), stream);
        count_kernel<<<(E + 255) / 256, 256, 0, stream>>>(ei, cnt, E);
        scan_kernel<<<1, 1024, 0, stream>>>(cnt, Nn);
        scatter_kernel<<<(E + 255) / 256, 256, 0, stream>>>(ei, cnt, eids, E);
        msg_kernel<<<(E + 255) / 256, 256, 0, stream>>>(
            ef, ea1, cut, ei, W1, W2, eids, out, msg, E);
        gather_kernel<<<(Nn + 3) / 4, 256, 0, stream>>>(cnt, msg, out, Nn);
    } else {
        // slow-but-correct fallback: zero T region then atomic scatter
        hipMemsetAsync(out, 0, (size_t)out_size * sizeof(float), stream);
        up_kernel<<<(Nn + 3) / 4, 256, 0, stream>>>(nf0, nf1, Wup0, Wup1, out, Nn);
        atomic_edge_kernel<<<(E + 255) / 256, 256, 0, stream>>>(
            ef, ea1, cut, ei, W1, W2, out, E);
    }
    finalize_kernel<<<(Nn + 3) / 4, 256, 0, stream>>>(attrs, Wsc0, Wsc1, Q0, Q1, out, Nn);
}